// Round 2
// baseline (238.052 us; speedup 1.0000x reference)
//
#include <hip/hip_runtime.h>
#include <stdint.h>

typedef float f32x4 __attribute__((ext_vector_type(4)));
typedef __bf16 bf16x8 __attribute__((ext_vector_type(8)));

__device__ __forceinline__ unsigned short f2bf(float f) {
  uint32_t u = __builtin_bit_cast(uint32_t, f);
  return (unsigned short)((u + 0x7fffu + ((u >> 16) & 1u)) >> 16);
}
__device__ __forceinline__ float bf2f(unsigned short s) {
  uint32_t u = ((uint32_t)s) << 16;
  return __builtin_bit_cast(float, u);
}

// ---- pack x,h (f32) -> xh bf16 [8192][2048] (x in cols 0:1024, h in 1024:2048)
__global__ void pack_xh(const float* __restrict__ x, const float* __restrict__ h,
                        unsigned short* __restrict__ xh) {
  const int n4 = (8192 * 1024) / 4;
  const float4* x4 = (const float4*)x;
  const float4* h4 = (const float4*)h;
  for (int idx = blockIdx.x * blockDim.x + threadIdx.x; idx < n4;
       idx += gridDim.x * blockDim.x) {
    float4 vx = x4[idx];
    float4 vh = h4[idx];
    int row = idx >> 8;            // 256 float4 per 1024-wide row
    int c  = (idx & 255) << 2;
    ushort4 px = { f2bf(vx.x), f2bf(vx.y), f2bf(vx.z), f2bf(vx.w) };
    ushort4 ph = { f2bf(vh.x), f2bf(vh.y), f2bf(vh.z), f2bf(vh.w) };
    *(ushort4*)(xh + (size_t)row * 2048 + c) = px;
    *(ushort4*)(xh + (size_t)row * 2048 + 1024 + c) = ph;
  }
}

// ---- transpose-pack one 1024x1024 f32 W (K x N) into bf16 Bt (N x K), at
// (rowOff, colOff) of a buffer with leading dim ldb.
__global__ void transpose_pack(const float* __restrict__ W, unsigned short* __restrict__ Bt,
                               int rowOff, int colOff, int ldb) {
  __shared__ float t[32][33];
  int n0 = blockIdx.x * 32, k0 = blockIdx.y * 32;
  for (int i = threadIdx.y; i < 32; i += 8)
    t[i][threadIdx.x] = W[(size_t)(k0 + i) * 1024 + n0 + threadIdx.x];
  __syncthreads();
  for (int i = threadIdx.y; i < 32; i += 8) {
    int n = n0 + i, k = k0 + threadIdx.x;
    Bt[(size_t)(rowOff + n) * ldb + colOff + k] = f2bf(t[threadIdx.x][i]);
  }
}

// ---- m97-structure GEMM: 128x128 tile, BK=32, 4 waves (2x2), 16x16x32 bf16 MFMA,
// global_load_lds width-16 staging, fused GRU epilogues.
// EPI==0: C = [x|h] @ [Wu|Wr]^T-packed;  cols<1024 -> u=sigmoid(C+bu) (bf16)
//                                        cols>=1024 -> hr = h*sigmoid(C+br) (bf16)
// EPI==1: C = [x|hr] @ Wc;  out = u*tanh(C+bc) + (1-u)*h  (f32)
template <int EPI>
__global__ __launch_bounds__(256) void gru_gemm(
    const unsigned short* __restrict__ xh,   // [8192][2048] bf16
    const unsigned short* __restrict__ hr,   // [8192][1024] bf16 (EPI==1)
    const unsigned short* __restrict__ Bt,   // [N][2048] bf16 (N-major, contiguous K)
    const float* __restrict__ bias0,         // bu or bc
    const float* __restrict__ bias1,         // br (EPI==0)
    const float* __restrict__ hfull,         // h f32 [8192][1024]
    const unsigned short* __restrict__ u_in, // (EPI==1)
    unsigned short* __restrict__ u_out,      // (EPI==0)
    unsigned short* __restrict__ hr_out,     // (EPI==0)
    float* __restrict__ out) {               // (EPI==1)
  constexpr int BK = 32;
  __shared__ unsigned short As[128 * BK];  // 8 KB, row-major [128][32], linear
  __shared__ unsigned short Bs[128 * BK];  // 8 KB, rows are N
  const int tid = threadIdx.x;
  const int l = tid & 63, w = tid >> 6;
  const int wr = w >> 1, wc = w & 1;
  const int row0 = blockIdx.y * 128, col0 = blockIdx.x * 128;

  f32x4 acc[4][4] = {};

  const int fr = l & 15;               // fragment row (A) / col-row (B)
  const int koff_b = (l >> 4) * 16;    // lane's k-chunk byte offset (8 bf16)

  for (int k0 = 0; k0 < 2048; k0 += BK) {
    __syncthreads();  // previous compute done before LDS overwrite
#pragma unroll
    for (int j = 0; j < 2; ++j) {  // A tile: 8 KB = 256 thr * 2 * 16 B
      int o = tid * 16 + j * 4096;
      int r = o >> 6, cb = o & 63;
      int kk = k0 + (cb >> 1);
      const unsigned short* srcA;
      if (EPI == 1 && kk >= 1024)
        srcA = hr + (size_t)(row0 + r) * 1024 + (kk - 1024);
      else
        srcA = xh + (size_t)(row0 + r) * 2048 + kk;
      __builtin_amdgcn_global_load_lds(
          (const __attribute__((address_space(1))) void*)srcA,
          (__attribute__((address_space(3))) void*)((char*)As + o), 16, 0, 0);
    }
#pragma unroll
    for (int j = 0; j < 2; ++j) {  // B tile
      int o = tid * 16 + j * 4096;
      int r = o >> 6, cb = o & 63;
      const unsigned short* srcB = Bt + (size_t)(col0 + r) * 2048 + k0 + (cb >> 1);
      __builtin_amdgcn_global_load_lds(
          (const __attribute__((address_space(1))) void*)srcB,
          (__attribute__((address_space(3))) void*)((char*)Bs + o), 16, 0, 0);
    }
    __syncthreads();  // compiler drains vmcnt before barrier

    bf16x8 a[4], b[4];
#pragma unroll
    for (int m = 0; m < 4; ++m)
      a[m] = *(const bf16x8*)((const char*)As + (wr * 64 + m * 16 + fr) * 64 + koff_b);
#pragma unroll
    for (int n = 0; n < 4; ++n)
      b[n] = *(const bf16x8*)((const char*)Bs + (wc * 64 + n * 16 + fr) * 64 + koff_b);
#pragma unroll
    for (int m = 0; m < 4; ++m)
#pragma unroll
      for (int n = 0; n < 4; ++n)
        acc[m][n] = __builtin_amdgcn_mfma_f32_16x16x32_bf16(a[m], b[n], acc[m][n], 0, 0, 0);
  }

  // epilogue: C/D layout col=lane&15, row=(lane>>4)*4+j  [verified m89/m91]
  const int rbase = row0 + wr * 64 + (l >> 4) * 4;
  const int cbase = col0 + wc * 64 + (l & 15);
#pragma unroll
  for (int m = 0; m < 4; ++m) {
#pragma unroll
    for (int n = 0; n < 4; ++n) {
      int col = cbase + n * 16;
#pragma unroll
      for (int j = 0; j < 4; ++j) {
        int row = rbase + m * 16 + j;
        float v = acc[m][n][j];
        if (EPI == 0) {
          if (col < 1024) {  // uniform per block (col0 multiple of 128)
            float uv = 1.f / (1.f + __expf(-(v + bias0[col])));
            u_out[(size_t)row * 1024 + col] = f2bf(uv);
          } else {
            int c2 = col - 1024;
            float rv = 1.f / (1.f + __expf(-(v + bias1[c2])));
            float hv = hfull[(size_t)row * 1024 + c2];
            hr_out[(size_t)row * 1024 + c2] = f2bf(hv * rv);
          }
        } else {
          float cp = tanhf(v + bias0[col]);
          float uv = bf2f(u_in[(size_t)row * 1024 + col]);
          float hv = hfull[(size_t)row * 1024 + col];
          out[(size_t)row * 1024 + col] = uv * cp + (1.f - uv) * hv;
        }
      }
    }
  }
}

extern "C" void kernel_launch(void* const* d_in, const int* in_sizes, int n_in,
                              void* d_out, int out_size, void* d_ws, size_t ws_size,
                              hipStream_t stream) {
  const float* x   = (const float*)d_in[0];
  const float* h   = (const float*)d_in[1];
  const float* Wxu = (const float*)d_in[2];
  const float* Whu = (const float*)d_in[3];
  const float* bu  = (const float*)d_in[4];
  const float* Wxr = (const float*)d_in[5];
  const float* Whr = (const float*)d_in[6];
  const float* br  = (const float*)d_in[7];
  const float* Wxc = (const float*)d_in[8];
  const float* Whc = (const float*)d_in[9];
  const float* bc  = (const float*)d_in[10];
  float* out = (float*)d_out;

  // workspace layout (bytes):
  char* ws = (char*)d_ws;
  unsigned short* xh  = (unsigned short*)(ws);              // 33,554,432
  unsigned short* Bt1 = (unsigned short*)(ws + 33554432);   //  8,388,608  [2048][2048]
  unsigned short* Bt2 = (unsigned short*)(ws + 41943040);   //  4,194,304  [1024][2048]
  unsigned short* ubf = (unsigned short*)(ws + 46137344);   // 16,777,216
  unsigned short* hr  = (unsigned short*)(ws + 62914560);   // 16,777,216  (ends 79,691,776)

  pack_xh<<<4096, 256, 0, stream>>>(x, h, xh);

  dim3 tb(32, 8), tg(32, 32);
  transpose_pack<<<tg, tb, 0, stream>>>(Wxu, Bt1, 0, 0, 2048);
  transpose_pack<<<tg, tb, 0, stream>>>(Whu, Bt1, 0, 1024, 2048);
  transpose_pack<<<tg, tb, 0, stream>>>(Wxr, Bt1, 1024, 0, 2048);
  transpose_pack<<<tg, tb, 0, stream>>>(Whr, Bt1, 1024, 1024, 2048);
  transpose_pack<<<tg, tb, 0, stream>>>(Wxc, Bt2, 0, 0, 2048);
  transpose_pack<<<tg, tb, 0, stream>>>(Whc, Bt2, 0, 1024, 2048);

  // GEMM1: [x|h](8192x2048) @ Bt1^T (2048x2048) -> u, hr
  gru_gemm<0><<<dim3(16, 64), 256, 0, stream>>>(xh, nullptr, Bt1, bu, br, h,
                                                nullptr, ubf, hr, nullptr);
  // GEMM2: [x|hr](8192x2048) @ Bt2^T (2048x1024) -> out
  gru_gemm<1><<<dim3(8, 64), 256, 0, stream>>>(xh, hr, Bt2, bc, nullptr, h,
                                               ubf, nullptr, nullptr, out);
}

// Round 4
// 198.867 us; speedup vs baseline: 1.1970x; 1.1970x over previous
//
#include <hip/hip_runtime.h>
#include <stdint.h>

typedef float f32x4 __attribute__((ext_vector_type(4)));
typedef __bf16 bf16x8 __attribute__((ext_vector_type(8)));

#define AS1 __attribute__((address_space(1)))
#define AS3 __attribute__((address_space(3)))

__device__ __forceinline__ unsigned short f2bf(float f) {
  uint32_t u = __builtin_bit_cast(uint32_t, f);
  return (unsigned short)((u + 0x7fffu + ((u >> 16) & 1u)) >> 16);
}
__device__ __forceinline__ float bf2f(unsigned short s) {
  uint32_t u = ((uint32_t)s) << 16;
  return __builtin_bit_cast(float, u);
}

// ---- pack x,h (f32) -> xh bf16 [8192][2048]
__global__ void pack_xh(const float* __restrict__ x, const float* __restrict__ h,
                        unsigned short* __restrict__ xh) {
  const int n4 = (8192 * 1024) / 4;
  const float4* x4 = (const float4*)x;
  const float4* h4 = (const float4*)h;
  for (int idx = blockIdx.x * blockDim.x + threadIdx.x; idx < n4;
       idx += gridDim.x * blockDim.x) {
    float4 vx = x4[idx];
    float4 vh = h4[idx];
    int row = idx >> 8;
    int c = (idx & 255) << 2;
    ushort4 px = { f2bf(vx.x), f2bf(vx.y), f2bf(vx.z), f2bf(vx.w) };
    ushort4 ph = { f2bf(vh.x), f2bf(vh.y), f2bf(vh.z), f2bf(vh.w) };
    *(ushort4*)(xh + (size_t)row * 2048 + c) = px;
    *(ushort4*)(xh + (size_t)row * 2048 + 1024 + c) = ph;
  }
}

// ---- all six W (K x N f32) -> bf16 Bt (N x K) transposes in one launch (z-indexed)
__global__ void transpose_pack6(const float* __restrict__ W0, const float* __restrict__ W1,
                                const float* __restrict__ W2, const float* __restrict__ W3,
                                const float* __restrict__ W4, const float* __restrict__ W5,
                                unsigned short* __restrict__ Bt1, unsigned short* __restrict__ Bt2) {
  __shared__ float t[32][33];
  const float* W; unsigned short* dst; int rowOff, colOff;
  switch (blockIdx.z) {
    case 0: W = W0; dst = Bt1; rowOff = 0;    colOff = 0;    break;
    case 1: W = W1; dst = Bt1; rowOff = 0;    colOff = 1024; break;
    case 2: W = W2; dst = Bt1; rowOff = 1024; colOff = 0;    break;
    case 3: W = W3; dst = Bt1; rowOff = 1024; colOff = 1024; break;
    case 4: W = W4; dst = Bt2; rowOff = 0;    colOff = 0;    break;
    default: W = W5; dst = Bt2; rowOff = 0;   colOff = 1024; break;
  }
  int n0 = blockIdx.x * 32, k0 = blockIdx.y * 32;
  for (int i = threadIdx.y; i < 32; i += 8)
    t[i][threadIdx.x] = W[(size_t)(k0 + i) * 1024 + n0 + threadIdx.x];
  __syncthreads();
  for (int i = threadIdx.y; i < 32; i += 8) {
    int n = n0 + i, k = k0 + threadIdx.x;
    dst[(size_t)(rowOff + n) * 2048 + colOff + k] = f2bf(t[threadIdx.x][i]);
  }
}

// ---- 256-wide 8-phase GEMM (T2 swizzle + T3/T4 counted-vmcnt + T5 setprio)
// A [8192][2048] bf16 (EPI1: k>=1024 half comes from hrA [8192][1024]);
// Bt [N][2048] bf16 N-major. BM=256, BK=64, 512 thr = 8 waves (2Mx4N).
// Per K-tile: 4 phases, quadrant snake (mh0nh0, mh0nh1, mh1nh1, mh1nh0).
template <int EPI, int BN>
__global__ __launch_bounds__(512, 1) void gru_gemm8(
    const unsigned short* __restrict__ xh,
    const unsigned short* __restrict__ hrA,
    const unsigned short* __restrict__ Bt,
    const float* __restrict__ bias0,
    const float* __restrict__ bias1,
    const float* __restrict__ hfull,
    const unsigned short* __restrict__ u_in,
    unsigned short* __restrict__ u_out,
    unsigned short* __restrict__ hr_out,
    float* __restrict__ out) {
  constexpr int WN = BN / 64;        // n-frags per wave: 4 (BN=256) or 2 (BN=128)
  constexpr int NH = WN / 2;         // frags per n-half
  constexpr int BLOADS = BN / 64;    // B gload_lds per thread per tile
  constexpr int TLOADS = 4 + BLOADS; // total loads per thread per tile
  constexpr int ABUF = 32768;        // 256 rows x 128 B
  constexpr int BBUF = BN * 128;
  constexpr int BUFSZ = ABUF + BBUF;
  constexpr int NKT = 32;            // 2048 / 64
  __shared__ __align__(128) char smem[2 * BUFSZ];

  const int tid = threadIdx.x;
  const int l = tid & 63;
  const int wid = tid >> 6;
  const int wr = wid >> 2;  // 0..1
  const int wc = wid & 3;   // 0..3
  const int row0 = blockIdx.y * 256;
  const int col0 = blockIdx.x * BN;

  // ---- staging source (inverse-swizzled global addr; LDS dest stays linear)
  const int srow = tid >> 3;                   // 0..63 (row within 64-row slab)
  const int s0 = (tid & 7) ^ (srow & 7);       // unswizzled 16B slot
  const char* pAx = (const char*)xh + (size_t)(row0 + srow) * 4096 + s0 * 16;
  const char* pAh = (EPI == 1)
      ? (const char*)hrA + (size_t)(row0 + srow) * 2048 + s0 * 16
      : (const char*)xh;
  const char* pB = (const char*)Bt + (size_t)(col0 + srow) * 4096 + s0 * 16;

  auto stage_tile = [&](int t, int p) {
    const size_t dA = (size_t)p * BUFSZ + (size_t)tid * 16;
    if (EPI == 1 && t >= 16) {
      const char* s = pAh + (size_t)(t - 16) * 128;
#pragma unroll
      for (int jj = 0; jj < 4; ++jj)
        __builtin_amdgcn_global_load_lds((const AS1 void*)(s + (size_t)jj * (64 * 2048)),
                                         (AS3 void*)(smem + dA + (size_t)jj * 8192), 16, 0, 0);
    } else {
      const char* s = pAx + (size_t)t * 128;
#pragma unroll
      for (int jj = 0; jj < 4; ++jj)
        __builtin_amdgcn_global_load_lds((const AS1 void*)(s + (size_t)jj * (64 * 4096)),
                                         (AS3 void*)(smem + dA + (size_t)jj * 8192), 16, 0, 0);
    }
    const char* sb = pB + (size_t)t * 128;
    const size_t dB = (size_t)p * BUFSZ + ABUF + (size_t)tid * 16;
#pragma unroll
    for (int jj = 0; jj < BLOADS; ++jj)
      __builtin_amdgcn_global_load_lds((const AS1 void*)(sb + (size_t)jj * (64 * 4096)),
                                       (AS3 void*)(smem + dB + (size_t)jj * 8192), 16, 0, 0);
  };

  // ---- swizzled ds_read fragment addressing
  const int lm = l & 15, hi4 = l >> 4;
  const int xorv = (l & 7) << 4;
  const int cb0 = (hi4 * 16) ^ xorv;        // ks=0 chunk byte
  const int cb1 = (64 + hi4 * 16) ^ xorv;   // ks=1
  const int aoff = (wr * 128 + lm) * 128;               // + m*2048 + cb
  const int boff = ABUF + (wc * (BN / 4) + lm) * 128;   // + n*2048 + cb

#define RD_A(P, M, KS) (*(const bf16x8*)(smem + (size_t)(P) * BUFSZ + aoff + (M) * 2048 + ((KS) ? cb1 : cb0)))
#define RD_B(P, N, KS) (*(const bf16x8*)(smem + (size_t)(P) * BUFSZ + boff + (N) * 2048 + ((KS) ? cb1 : cb0)))

  f32x4 acc[8][WN] = {};

  // ---- prologue: stage tiles 0,1; wait tile0 only (tile1 stays in flight)
  stage_tile(0, 0);
  stage_tile(1, 1);
  asm volatile("s_waitcnt vmcnt(%0)" ::"i"(TLOADS) : "memory");
  __builtin_amdgcn_s_barrier();
  asm volatile("" ::: "memory");  // fence: P0 ds_reads must not hoist above barrier

  for (int g = 0; g < NKT; ++g) {
    const int p = g & 1;
    bf16x8 a0[4][2], a1[4][2], b0[NH][2], b1[NH][2];

    // ---- P0: read A-half0 + B-half0; MFMA (mh0,nh0)
#pragma unroll
    for (int m = 0; m < 4; ++m) { a0[m][0] = RD_A(p, m, 0); a0[m][1] = RD_A(p, m, 1); }
#pragma unroll
    for (int n = 0; n < NH; ++n) { b0[n][0] = RD_B(p, n, 0); b0[n][1] = RD_B(p, n, 1); }
    __builtin_amdgcn_s_barrier();
    asm volatile("s_waitcnt lgkmcnt(0)" ::: "memory");
    __builtin_amdgcn_s_setprio(1);
#pragma unroll
    for (int m = 0; m < 4; ++m)
#pragma unroll
      for (int n = 0; n < NH; ++n) {
        acc[m][n] = __builtin_amdgcn_mfma_f32_16x16x32_bf16(a0[m][0], b0[n][0], acc[m][n], 0, 0, 0);
        acc[m][n] = __builtin_amdgcn_mfma_f32_16x16x32_bf16(a0[m][1], b0[n][1], acc[m][n], 0, 0, 0);
      }
    __builtin_amdgcn_s_setprio(0);
    __builtin_amdgcn_s_barrier();

    // ---- P1: read B-half1; MFMA (mh0,nh1)
#pragma unroll
    for (int n = 0; n < NH; ++n) { b1[n][0] = RD_B(p, NH + n, 0); b1[n][1] = RD_B(p, NH + n, 1); }
    __builtin_amdgcn_s_barrier();
    asm volatile("s_waitcnt lgkmcnt(0)" ::: "memory");
    __builtin_amdgcn_s_setprio(1);
#pragma unroll
    for (int m = 0; m < 4; ++m)
#pragma unroll
      for (int n = 0; n < NH; ++n) {
        acc[m][NH + n] = __builtin_amdgcn_mfma_f32_16x16x32_bf16(a0[m][0], b1[n][0], acc[m][NH + n], 0, 0, 0);
        acc[m][NH + n] = __builtin_amdgcn_mfma_f32_16x16x32_bf16(a0[m][1], b1[n][1], acc[m][NH + n], 0, 0, 0);
      }
    __builtin_amdgcn_s_setprio(0);
    __builtin_amdgcn_s_barrier();

    // ---- P2: read A-half1; MFMA (mh1,nh1)  (reuse b1)
#pragma unroll
    for (int m = 0; m < 4; ++m) { a1[m][0] = RD_A(p, 4 + m, 0); a1[m][1] = RD_A(p, 4 + m, 1); }
    __builtin_amdgcn_s_barrier();
    asm volatile("s_waitcnt lgkmcnt(0)" ::: "memory");
    __builtin_amdgcn_s_setprio(1);
#pragma unroll
    for (int m = 0; m < 4; ++m)
#pragma unroll
      for (int n = 0; n < NH; ++n) {
        acc[4 + m][NH + n] = __builtin_amdgcn_mfma_f32_16x16x32_bf16(a1[m][0], b1[n][0], acc[4 + m][NH + n], 0, 0, 0);
        acc[4 + m][NH + n] = __builtin_amdgcn_mfma_f32_16x16x32_bf16(a1[m][1], b1[n][1], acc[4 + m][NH + n], 0, 0, 0);
      }
    __builtin_amdgcn_s_setprio(0);
    __builtin_amdgcn_s_barrier();

    // ---- P3: no ds_reads (all buf-p reads completed by P2 barrier) ->
    // stage tile g+2 into buf p; MFMA (mh1,nh0) reusing a1,b0; counted vmcnt.
    if (g + 2 < NKT) stage_tile(g + 2, p);
    __builtin_amdgcn_s_barrier();
    __builtin_amdgcn_s_setprio(1);
#pragma unroll
    for (int m = 0; m < 4; ++m)
#pragma unroll
      for (int n = 0; n < NH; ++n) {
        acc[4 + m][n] = __builtin_amdgcn_mfma_f32_16x16x32_bf16(a1[m][0], b0[n][0], acc[4 + m][n], 0, 0, 0);
        acc[4 + m][n] = __builtin_amdgcn_mfma_f32_16x16x32_bf16(a1[m][1], b0[n][1], acc[4 + m][n], 0, 0, 0);
      }
    __builtin_amdgcn_s_setprio(0);
    if (g + 2 < NKT) {
      asm volatile("s_waitcnt vmcnt(%0)" ::"i"(TLOADS) : "memory");  // tile g+1 landed, g+2 in flight
    } else if (g + 1 < NKT) {
      asm volatile("s_waitcnt vmcnt(0)" ::: "memory");               // drain last prefetch
    }
    __builtin_amdgcn_s_barrier();
    asm volatile("" ::: "memory");  // fence: next P0 ds_reads must not hoist above barrier
  }

  // ---- epilogue: C/D layout col=lane&15, row=(lane>>4)*4+j
#pragma unroll
  for (int m = 0; m < 8; ++m) {
#pragma unroll
    for (int n = 0; n < WN; ++n) {
      const int col = col0 + wc * (BN / 4) + n * 16 + lm;
      const int rowb = row0 + wr * 128 + m * 16 + hi4 * 4;
#pragma unroll
      for (int j = 0; j < 4; ++j) {
        const int row = rowb + j;
        float v = acc[m][n][j];
        if (EPI == 0) {
          if (col < 1024) {
            float uv = 1.f / (1.f + __expf(-(v + bias0[col])));
            u_out[(size_t)row * 1024 + col] = f2bf(uv);
          } else {
            int c2 = col - 1024;
            float rv = 1.f / (1.f + __expf(-(v + bias1[c2])));
            float hv = hfull[(size_t)row * 1024 + c2];
            hr_out[(size_t)row * 1024 + c2] = f2bf(hv * rv);
          }
        } else {
          float cp = tanhf(v + bias0[col]);
          float uv = bf2f(u_in[(size_t)row * 1024 + col]);
          float hv = hfull[(size_t)row * 1024 + col];
          out[(size_t)row * 1024 + col] = uv * cp + (1.f - uv) * hv;
        }
      }
    }
  }
#undef RD_A
#undef RD_B
}

extern "C" void kernel_launch(void* const* d_in, const int* in_sizes, int n_in,
                              void* d_out, int out_size, void* d_ws, size_t ws_size,
                              hipStream_t stream) {
  const float* x   = (const float*)d_in[0];
  const float* h   = (const float*)d_in[1];
  const float* Wxu = (const float*)d_in[2];
  const float* Whu = (const float*)d_in[3];
  const float* bu  = (const float*)d_in[4];
  const float* Wxr = (const float*)d_in[5];
  const float* Whr = (const float*)d_in[6];
  const float* br  = (const float*)d_in[7];
  const float* Wxc = (const float*)d_in[8];
  const float* Whc = (const float*)d_in[9];
  const float* bc  = (const float*)d_in[10];
  float* out = (float*)d_out;

  char* ws = (char*)d_ws;
  unsigned short* xh  = (unsigned short*)(ws);              // 33,554,432 B
  unsigned short* Bt1 = (unsigned short*)(ws + 33554432);   //  8,388,608 B [2048][2048]
  unsigned short* Bt2 = (unsigned short*)(ws + 41943040);   //  4,194,304 B [1024][2048]
  unsigned short* ubf = (unsigned short*)(ws + 46137344);   // 16,777,216 B
  unsigned short* hrb = (unsigned short*)(ws + 62914560);   // 16,777,216 B

  pack_xh<<<4096, 256, 0, stream>>>(x, h, xh);
  transpose_pack6<<<dim3(32, 32, 6), dim3(32, 8), 0, stream>>>(Wxu, Whu, Wxr, Whr, Wxc, Whc, Bt1, Bt2);

  // GEMM1: [x|h](8192x2048) @ Bt1 (2048 rows) -> u (bf16), hr=h*r (bf16)
  gru_gemm8<0, 256><<<dim3(8, 32), 512, 0, stream>>>(xh, nullptr, Bt1, bu, br, h,
                                                     nullptr, ubf, hrb, nullptr);
  // GEMM2: [x|hr](8192x2048) @ Bt2 (1024 rows) -> out f32
  gru_gemm8<1, 128><<<dim3(8, 32), 512, 0, stream>>>(xh, hrb, Bt2, bc, nullptr, h,
                                                     ubf, nullptr, nullptr, out);
}

// Round 6
// 191.022 us; speedup vs baseline: 1.2462x; 1.0411x over previous
//
#include <hip/hip_runtime.h>
#include <stdint.h>

typedef float f32x4 __attribute__((ext_vector_type(4)));
typedef __bf16 bf16x8 __attribute__((ext_vector_type(8)));

#define AS1 __attribute__((address_space(1)))
#define AS3 __attribute__((address_space(3)))

__device__ __forceinline__ unsigned short f2bf(float f) {
  uint32_t u = __builtin_bit_cast(uint32_t, f);
  return (unsigned short)((u + 0x7fffu + ((u >> 16) & 1u)) >> 16);
}
__device__ __forceinline__ float bf2f(unsigned short s) {
  uint32_t u = ((uint32_t)s) << 16;
  return __builtin_bit_cast(float, u);
}

// ---- pack x,h (f32) -> xh bf16 [8192][2048]
__global__ void pack_xh(const float* __restrict__ x, const float* __restrict__ h,
                        unsigned short* __restrict__ xh) {
  const int n4 = (8192 * 1024) / 4;
  const float4* x4 = (const float4*)x;
  const float4* h4 = (const float4*)h;
  for (int idx = blockIdx.x * blockDim.x + threadIdx.x; idx < n4;
       idx += gridDim.x * blockDim.x) {
    float4 vx = x4[idx];
    float4 vh = h4[idx];
    int row = idx >> 8;
    int c = (idx & 255) << 2;
    ushort4 px = { f2bf(vx.x), f2bf(vx.y), f2bf(vx.z), f2bf(vx.w) };
    ushort4 ph = { f2bf(vh.x), f2bf(vh.y), f2bf(vh.z), f2bf(vh.w) };
    *(ushort4*)(xh + (size_t)row * 2048 + c) = px;
    *(ushort4*)(xh + (size_t)row * 2048 + 1024 + c) = ph;
  }
}

// ---- all six W (K x N f32) -> bf16 Bt (N x K) transposes in one launch
__global__ void transpose_pack6(const float* __restrict__ W0, const float* __restrict__ W1,
                                const float* __restrict__ W2, const float* __restrict__ W3,
                                const float* __restrict__ W4, const float* __restrict__ W5,
                                unsigned short* __restrict__ Bt1, unsigned short* __restrict__ Bt2) {
  __shared__ float t[32][33];
  const float* W; unsigned short* dst; int rowOff, colOff;
  switch (blockIdx.z) {
    case 0: W = W0; dst = Bt1; rowOff = 0;    colOff = 0;    break;
    case 1: W = W1; dst = Bt1; rowOff = 0;    colOff = 1024; break;
    case 2: W = W2; dst = Bt1; rowOff = 1024; colOff = 0;    break;
    case 3: W = W3; dst = Bt1; rowOff = 1024; colOff = 1024; break;
    case 4: W = W4; dst = Bt2; rowOff = 0;    colOff = 0;    break;
    default: W = W5; dst = Bt2; rowOff = 0;   colOff = 1024; break;
  }
  int n0 = blockIdx.x * 32, k0 = blockIdx.y * 32;
  for (int i = threadIdx.y; i < 32; i += 8)
    t[i][threadIdx.x] = W[(size_t)(k0 + i) * 1024 + n0 + threadIdx.x];
  __syncthreads();
  for (int i = threadIdx.y; i < 32; i += 8) {
    int n = n0 + i, k = k0 + threadIdx.x;
    dst[(size_t)(rowOff + n) * 2048 + colOff + k] = f2bf(t[threadIdx.x][i]);
  }
}

// ---- m201 8-phase GEMM: BM=256, BK=64, 8 waves (2Mx4N), 2 K-tiles/iter,
// 1 half-tile staged per phase, vmcnt(VCNT) at ph3/ph7 only, T2 swizzle, T5 setprio.
// SLAB-ALIGNED wave ownership: A read-quadrants and B read-halves coincide with
// the 128-row staging halves (WAR-safety of the per-phase stage stream).
template <int EPI, int BN>
__global__ __launch_bounds__(512, 1) void gru_gemm8(
    const unsigned short* __restrict__ xh,
    const unsigned short* __restrict__ hrA,
    const unsigned short* __restrict__ Bt,
    const float* __restrict__ bias0,
    const float* __restrict__ bias1,
    const float* __restrict__ hfull,
    const unsigned short* __restrict__ u_in,
    unsigned short* __restrict__ u_out,
    unsigned short* __restrict__ hr_out,
    float* __restrict__ out) {
  constexpr int WN = BN / 64;   // 4 (BN=256) or 2 (BN=128)
  constexpr int NH = WN / 2;
  constexpr int ABUF = 32768;   // 256 rows x 128 B
  constexpr int BBUF = BN * 128;
  constexpr int BUFSZ = ABUF + BBUF;
  constexpr int NKT = 32;       // 2048 / 64
  constexpr int NIT = NKT / 2;
  constexpr int VCNT = (BN == 256) ? 6 : 4;
  __shared__ __align__(128) char smem[2 * BUFSZ];

  const int tid = threadIdx.x;
  const int l = tid & 63;
  const int wid = tid >> 6;
  const int wr = wid >> 2, wc = wid & 3;
  const int row0 = blockIdx.y * 256;
  const int col0 = blockIdx.x * BN;

  // staging source (inverse-swizzled global addr; LDS dest linear)
  const int srow = tid >> 3;
  const int s0 = (tid & 7) ^ (srow & 7);
  const char* pAx = (const char*)xh + (size_t)(row0 + srow) * 4096 + s0 * 16;
  const char* pAh = (EPI == 1)
      ? (const char*)hrA + (size_t)(row0 + srow) * 2048 + s0 * 16
      : (const char*)xh;
  const char* pB = (const char*)Bt + (size_t)(col0 + srow) * 4096 + s0 * 16;

  // one half-tile = 128 rows x 64 cols bf16 = 2 global_load_lds per thread
  auto stage_A = [&](int t, int half, int p) {
    if (t >= NKT) return;
    const size_t d = (size_t)p * BUFSZ + (size_t)half * 16384 + (size_t)tid * 16;
    if (EPI == 1 && t >= 16) {
      const char* s = pAh + (size_t)(t - 16) * 128 + (size_t)half * (128 * 2048);
#pragma unroll
      for (int jj = 0; jj < 2; ++jj)
        __builtin_amdgcn_global_load_lds((const AS1 void*)(s + (size_t)jj * (64 * 2048)),
                                         (AS3 void*)(smem + d + (size_t)jj * 8192), 16, 0, 0);
    } else {
      const char* s = pAx + (size_t)t * 128 + (size_t)half * (128 * 4096);
#pragma unroll
      for (int jj = 0; jj < 2; ++jj)
        __builtin_amdgcn_global_load_lds((const AS1 void*)(s + (size_t)jj * (64 * 4096)),
                                         (AS3 void*)(smem + d + (size_t)jj * 8192), 16, 0, 0);
    }
  };
  auto stage_B = [&](int t, int half, int p) {
    if (t >= NKT) return;
    const char* s = pB + (size_t)t * 128 + (size_t)half * (128 * 4096);
    const size_t d = (size_t)p * BUFSZ + ABUF + (size_t)half * 16384 + (size_t)tid * 16;
#pragma unroll
    for (int jj = 0; jj < 2; ++jj)
      __builtin_amdgcn_global_load_lds((const AS1 void*)(s + (size_t)jj * (64 * 4096)),
                                       (AS3 void*)(smem + d + (size_t)jj * 8192), 16, 0, 0);
  };

  // swizzled ds_read fragment addressing (slab-aligned ownership)
  const int lm = l & 15, hi4 = l >> 4;
  const int xorv = (l & 7) << 4;
  const int cb0 = (hi4 * 16) ^ xorv;
  const int cb1 = (64 + hi4 * 16) ^ xorv;
  const int aslab = (wr * 64 + lm) * 128;                 // wave's base row in h0
  const int bslab = ABUF + (wc * 16 * NH + lm) * 128;     // wave's base col-row in h0

#define AROW(M) (((M) < 4) ? (M) * 16 : 128 + ((M) - 4) * 16)
#define BROW(N) (((N) < NH) ? (N) * 16 : BN / 2 + ((N) - NH) * 16)
#define RD_A(P, M, KS) (*(const bf16x8*)(smem + (size_t)(P) * BUFSZ + aslab + AROW(M) * 128 + ((KS) ? cb1 : cb0)))
#define RD_B(P, N, KS) (*(const bf16x8*)(smem + (size_t)(P) * BUFSZ + bslab + BROW(N) * 128 + ((KS) ? cb1 : cb0)))
#define MFMA_(D, AV, BV) D = __builtin_amdgcn_mfma_f32_16x16x32_bf16(AV, BV, D, 0, 0, 0)
#define PHASE_TOP() do { __builtin_amdgcn_s_barrier(); \
    asm volatile("s_waitcnt lgkmcnt(0)" ::: "memory"); \
    __builtin_amdgcn_sched_barrier(0); \
    __builtin_amdgcn_s_setprio(1); } while (0)
#define PHASE_BOT() do { __builtin_amdgcn_s_setprio(0); \
    __builtin_amdgcn_s_barrier(); \
    asm volatile("" ::: "memory"); } while (0)

  f32x4 acc[8][WN] = {};
  bf16x8 a0[4][2], a1[4][2], b0[NH][2], b1[NH][2];

  // ---- prologue: tile0 fully + tile1 {Ah0,Bh0[,Bh1]}; wait tile0 landed
  stage_A(0, 0, 0); stage_A(0, 1, 0); stage_B(0, 0, 0);
  if (BN == 256) stage_B(0, 1, 0);
  stage_A(1, 0, 1); stage_B(1, 0, 1);
  if (BN == 256) stage_B(1, 1, 1);
  asm volatile("s_waitcnt vmcnt(%0)" ::"i"(VCNT) : "memory");
  __builtin_amdgcn_s_barrier();
  asm volatile("" ::: "memory");

  for (int it = 0; it < NIT; ++it) {
    const int o = 2 * it + 1, e2 = 2 * it + 2, o2 = 2 * it + 3;
    const bool last = (it == NIT - 1);

    // ---- ph0: reads a0(e.Ah0),b0(e.Bh0) [buf0]; stage o.Ah1 -> buf1; Q00(e)
#pragma unroll
    for (int m = 0; m < 4; ++m) { a0[m][0] = RD_A(0, m, 0); a0[m][1] = RD_A(0, m, 1); }
#pragma unroll
    for (int n = 0; n < NH; ++n) { b0[n][0] = RD_B(0, n, 0); b0[n][1] = RD_B(0, n, 1); }
    stage_A(o, 1, 1);
    PHASE_TOP();
#pragma unroll
    for (int m = 0; m < 4; ++m)
#pragma unroll
      for (int n = 0; n < NH; ++n) { MFMA_(acc[m][n], a0[m][0], b0[n][0]); MFMA_(acc[m][n], a0[m][1], b0[n][1]); }
    PHASE_BOT();

    // ---- ph1: reads b1(e.Bh1) [buf0]; stage e2.Ah0 -> buf0; Q01(e)
#pragma unroll
    for (int n = 0; n < NH; ++n) { b1[n][0] = RD_B(0, NH + n, 0); b1[n][1] = RD_B(0, NH + n, 1); }
    stage_A(e2, 0, 0);
    PHASE_TOP();
#pragma unroll
    for (int m = 0; m < 4; ++m)
#pragma unroll
      for (int n = 0; n < NH; ++n) { MFMA_(acc[m][NH + n], a0[m][0], b1[n][0]); MFMA_(acc[m][NH + n], a0[m][1], b1[n][1]); }
    PHASE_BOT();

    // ---- ph2: reads a1(e.Ah1) [buf0]; stage e2.Bh0 -> buf0; Q11(e)
#pragma unroll
    for (int m = 0; m < 4; ++m) { a1[m][0] = RD_A(0, 4 + m, 0); a1[m][1] = RD_A(0, 4 + m, 1); }
    stage_B(e2, 0, 0);
    PHASE_TOP();
#pragma unroll
    for (int m = 0; m < 4; ++m)
#pragma unroll
      for (int n = 0; n < NH; ++n) { MFMA_(acc[4 + m][NH + n], a1[m][0], b1[n][0]); MFMA_(acc[4 + m][NH + n], a1[m][1], b1[n][1]); }
    PHASE_BOT();

    // ---- ph3: no reads; stage e2.Bh1 -> buf0 (BN=256); Q10(e); vmcnt checkpoint
    if (BN == 256) stage_B(e2, 1, 0);
    PHASE_TOP();
#pragma unroll
    for (int m = 0; m < 4; ++m)
#pragma unroll
      for (int n = 0; n < NH; ++n) { MFMA_(acc[4 + m][n], a1[m][0], b0[n][0]); MFMA_(acc[4 + m][n], a1[m][1], b0[n][1]); }
    __builtin_amdgcn_s_setprio(0);
    if (last) asm volatile("s_waitcnt vmcnt(0)" ::: "memory");
    else      asm volatile("s_waitcnt vmcnt(%0)" ::"i"(VCNT) : "memory");
    __builtin_amdgcn_s_barrier();
    asm volatile("" ::: "memory");

    // ---- ph4: reads a0(o.Ah0),b0(o.Bh0) [buf1]; stage e2.Ah1 -> buf0; Q00(o)
#pragma unroll
    for (int m = 0; m < 4; ++m) { a0[m][0] = RD_A(1, m, 0); a0[m][1] = RD_A(1, m, 1); }
#pragma unroll
    for (int n = 0; n < NH; ++n) { b0[n][0] = RD_B(1, n, 0); b0[n][1] = RD_B(1, n, 1); }
    stage_A(e2, 1, 0);
    PHASE_TOP();
#pragma unroll
    for (int m = 0; m < 4; ++m)
#pragma unroll
      for (int n = 0; n < NH; ++n) { MFMA_(acc[m][n], a0[m][0], b0[n][0]); MFMA_(acc[m][n], a0[m][1], b0[n][1]); }
    PHASE_BOT();

    // ---- ph5: reads b1(o.Bh1) [buf1]; stage o2.Ah0 -> buf1; Q01(o)
#pragma unroll
    for (int n = 0; n < NH; ++n) { b1[n][0] = RD_B(1, NH + n, 0); b1[n][1] = RD_B(1, NH + n, 1); }
    stage_A(o2, 0, 1);
    PHASE_TOP();
#pragma unroll
    for (int m = 0; m < 4; ++m)
#pragma unroll
      for (int n = 0; n < NH; ++n) { MFMA_(acc[m][NH + n], a0[m][0], b1[n][0]); MFMA_(acc[m][NH + n], a0[m][1], b1[n][1]); }
    PHASE_BOT();

    // ---- ph6: reads a1(o.Ah1) [buf1]; stage o2.Bh0 -> buf1; Q11(o)
#pragma unroll
    for (int m = 0; m < 4; ++m) { a1[m][0] = RD_A(1, 4 + m, 0); a1[m][1] = RD_A(1, 4 + m, 1); }
    stage_B(o2, 0, 1);
    PHASE_TOP();
#pragma unroll
    for (int m = 0; m < 4; ++m)
#pragma unroll
      for (int n = 0; n < NH; ++n) { MFMA_(acc[4 + m][NH + n], a1[m][0], b1[n][0]); MFMA_(acc[4 + m][NH + n], a1[m][1], b1[n][1]); }
    PHASE_BOT();

    // ---- ph7: no reads; stage o2.Bh1 -> buf1 (BN=256); Q10(o); vmcnt checkpoint
    if (BN == 256) stage_B(o2, 1, 1);
    PHASE_TOP();
#pragma unroll
    for (int m = 0; m < 4; ++m)
#pragma unroll
      for (int n = 0; n < NH; ++n) { MFMA_(acc[4 + m][n], a1[m][0], b0[n][0]); MFMA_(acc[4 + m][n], a1[m][1], b0[n][1]); }
    __builtin_amdgcn_s_setprio(0);
    if (!last) asm volatile("s_waitcnt vmcnt(%0)" ::"i"(VCNT) : "memory");
    __builtin_amdgcn_s_barrier();
    asm volatile("" ::: "memory");
  }

  // ---- epilogue: C/D layout col=lane&15, row=(lane>>4)*4+j; slab ownership
#pragma unroll
  for (int m = 0; m < 8; ++m) {
#pragma unroll
    for (int n = 0; n < WN; ++n) {
      const int col = col0 + wc * 16 * NH + BROW(n) + lm;
      const int rowb = row0 + wr * 64 + AROW(m) + hi4 * 4;
#pragma unroll
      for (int j = 0; j < 4; ++j) {
        const int row = rowb + j;
        float v = acc[m][n][j];
        if (EPI == 0) {
          if (col < 1024) {
            float uv = 1.f / (1.f + __expf(-(v + bias0[col])));
            u_out[(size_t)row * 1024 + col] = f2bf(uv);
          } else {
            int c2 = col - 1024;
            float rv = 1.f / (1.f + __expf(-(v + bias1[c2])));
            float hv = hfull[(size_t)row * 1024 + c2];
            hr_out[(size_t)row * 1024 + c2] = f2bf(hv * rv);
          }
        } else {
          float cp = tanhf(v + bias0[col]);
          float uv = bf2f(u_in[(size_t)row * 1024 + col]);
          float hv = hfull[(size_t)row * 1024 + col];
          out[(size_t)row * 1024 + col] = uv * cp + (1.f - uv) * hv;
        }
      }
    }
  }
#undef AROW
#undef BROW
#undef RD_A
#undef RD_B
#undef MFMA_
#undef PHASE_TOP
#undef PHASE_BOT
}

extern "C" void kernel_launch(void* const* d_in, const int* in_sizes, int n_in,
                              void* d_out, int out_size, void* d_ws, size_t ws_size,
                              hipStream_t stream) {
  const float* x   = (const float*)d_in[0];
  const float* h   = (const float*)d_in[1];
  const float* Wxu = (const float*)d_in[2];
  const float* Whu = (const float*)d_in[3];
  const float* bu  = (const float*)d_in[4];
  const float* Wxr = (const float*)d_in[5];
  const float* Whr = (const float*)d_in[6];
  const float* br  = (const float*)d_in[7];
  const float* Wxc = (const float*)d_in[8];
  const float* Whc = (const float*)d_in[9];
  const float* bc  = (const float*)d_in[10];
  float* out = (float*)d_out;

  char* ws = (char*)d_ws;
  unsigned short* xh  = (unsigned short*)(ws);              // 33,554,432 B
  unsigned short* Bt1 = (unsigned short*)(ws + 33554432);   //  8,388,608 B [2048][2048]
  unsigned short* Bt2 = (unsigned short*)(ws + 41943040);   //  4,194,304 B [1024][2048]
  unsigned short* ubf = (unsigned short*)(ws + 46137344);   // 16,777,216 B
  unsigned short* hrb = (unsigned short*)(ws + 62914560);   // 16,777,216 B

  pack_xh<<<4096, 256, 0, stream>>>(x, h, xh);
  transpose_pack6<<<dim3(32, 32, 6), dim3(32, 8), 0, stream>>>(Wxu, Whu, Wxr, Whr, Wxc, Whc, Bt1, Bt2);

  // GEMM1: [x|h](8192x2048) @ Bt1 -> u (bf16), hr=h*r (bf16)
  gru_gemm8<0, 256><<<dim3(8, 32), 512, 0, stream>>>(xh, nullptr, Bt1, bu, br, h,
                                                     nullptr, ubf, hrb, nullptr);
  // GEMM2: [x|hr](8192x2048) @ Bt2 -> out f32
  gru_gemm8<1, 128><<<dim3(8, 32), 512, 0, stream>>>(xh, hrb, Bt2, bc, nullptr, h,
                                                     ubf, nullptr, nullptr, out);
}

// Round 7
// 189.172 us; speedup vs baseline: 1.2584x; 1.0098x over previous
//
#include <hip/hip_runtime.h>
#include <stdint.h>

typedef float f32x4 __attribute__((ext_vector_type(4)));
typedef __bf16 bf16x8 __attribute__((ext_vector_type(8)));

#define AS1 __attribute__((address_space(1)))
#define AS3 __attribute__((address_space(3)))

__device__ __forceinline__ unsigned short f2bf(float f) {
  uint32_t u = __builtin_bit_cast(uint32_t, f);
  return (unsigned short)((u + 0x7fffu + ((u >> 16) & 1u)) >> 16);
}
__device__ __forceinline__ float bf2f(unsigned short s) {
  uint32_t u = ((uint32_t)s) << 16;
  return __builtin_bit_cast(float, u);
}

// ---- pack x,h (f32) -> xh bf16 [8192][2048]
__global__ void pack_xh(const float* __restrict__ x, const float* __restrict__ h,
                        unsigned short* __restrict__ xh) {
  const int n4 = (8192 * 1024) / 4;
  const float4* x4 = (const float4*)x;
  const float4* h4 = (const float4*)h;
  for (int idx = blockIdx.x * blockDim.x + threadIdx.x; idx < n4;
       idx += gridDim.x * blockDim.x) {
    float4 vx = x4[idx];
    float4 vh = h4[idx];
    int row = idx >> 8;
    int c = (idx & 255) << 2;
    ushort4 px = { f2bf(vx.x), f2bf(vx.y), f2bf(vx.z), f2bf(vx.w) };
    ushort4 ph = { f2bf(vh.x), f2bf(vh.y), f2bf(vh.z), f2bf(vh.w) };
    *(ushort4*)(xh + (size_t)row * 2048 + c) = px;
    *(ushort4*)(xh + (size_t)row * 2048 + 1024 + c) = ph;
  }
}

// ---- all six W (K x N f32) -> bf16 Bt (N x K) transposes in one launch
__global__ void transpose_pack6(const float* __restrict__ W0, const float* __restrict__ W1,
                                const float* __restrict__ W2, const float* __restrict__ W3,
                                const float* __restrict__ W4, const float* __restrict__ W5,
                                unsigned short* __restrict__ Bt1, unsigned short* __restrict__ Bt2) {
  __shared__ float t[32][33];
  const float* W; unsigned short* dst; int rowOff, colOff;
  switch (blockIdx.z) {
    case 0: W = W0; dst = Bt1; rowOff = 0;    colOff = 0;    break;
    case 1: W = W1; dst = Bt1; rowOff = 0;    colOff = 1024; break;
    case 2: W = W2; dst = Bt1; rowOff = 1024; colOff = 0;    break;
    case 3: W = W3; dst = Bt1; rowOff = 1024; colOff = 1024; break;
    case 4: W = W4; dst = Bt2; rowOff = 0;    colOff = 0;    break;
    default: W = W5; dst = Bt2; rowOff = 0;   colOff = 1024; break;
  }
  int n0 = blockIdx.x * 32, k0 = blockIdx.y * 32;
  for (int i = threadIdx.y; i < 32; i += 8)
    t[i][threadIdx.x] = W[(size_t)(k0 + i) * 1024 + n0 + threadIdx.x];
  __syncthreads();
  for (int i = threadIdx.y; i < 32; i += 8) {
    int n = n0 + i, k = k0 + threadIdx.x;
    dst[(size_t)(rowOff + n) * 2048 + colOff + k] = f2bf(t[threadIdx.x][i]);
  }
}

// ---- 8-phase GEMM, compiler-managed lgkm waits, 1 barrier/phase, late read-ahead.
// BM=256, BK=64, 8 waves (2Mx4N), 2 K-tiles/iter, vmcnt(VCNT) at ph3/ph7 only,
// T2 both-sides swizzle, T5 setprio. Slab-aligned wave ownership (R5 ledger).
template <int EPI, int BN>
__global__ __launch_bounds__(512, 1) void gru_gemm8(
    const unsigned short* __restrict__ xh,
    const unsigned short* __restrict__ hrA,
    const unsigned short* __restrict__ Bt,
    const float* __restrict__ bias0,
    const float* __restrict__ bias1,
    const float* __restrict__ hfull,
    const unsigned short* __restrict__ u_in,
    unsigned short* __restrict__ u_out,
    unsigned short* __restrict__ hr_out,
    float* __restrict__ out) {
  constexpr int WN = BN / 64;
  constexpr int NH = WN / 2;
  constexpr int ABUF = 32768;
  constexpr int BBUF = BN * 128;
  constexpr int BUFSZ = ABUF + BBUF;
  constexpr int NKT = 32;
  constexpr int NIT = NKT / 2;
  constexpr int VCNT = (BN == 256) ? 6 : 4;
  __shared__ __align__(128) char smem[2 * BUFSZ];

  const int tid = threadIdx.x;
  const int l = tid & 63;
  const int wid = tid >> 6;
  const int wr = wid >> 2, wc = wid & 3;
  const int row0 = blockIdx.y * 256;
  const int col0 = blockIdx.x * BN;

  // staging source (inverse-swizzled global addr; LDS dest linear)
  const int srow = tid >> 3;
  const int s0 = (tid & 7) ^ (srow & 7);
  const char* pAx = (const char*)xh + (size_t)(row0 + srow) * 4096 + s0 * 16;
  const char* pAh = (EPI == 1)
      ? (const char*)hrA + (size_t)(row0 + srow) * 2048 + s0 * 16
      : (const char*)xh;
  const char* pB = (const char*)Bt + (size_t)(col0 + srow) * 4096 + s0 * 16;

  auto stage_A = [&](int t, int half, int p) {
    if (t >= NKT) return;
    const size_t d = (size_t)p * BUFSZ + (size_t)half * 16384 + (size_t)tid * 16;
    if (EPI == 1 && t >= 16) {
      const char* s = pAh + (size_t)(t - 16) * 128 + (size_t)half * (128 * 2048);
#pragma unroll
      for (int jj = 0; jj < 2; ++jj)
        __builtin_amdgcn_global_load_lds((const AS1 void*)(s + (size_t)jj * (64 * 2048)),
                                         (AS3 void*)(smem + d + (size_t)jj * 8192), 16, 0, 0);
    } else {
      const char* s = pAx + (size_t)t * 128 + (size_t)half * (128 * 4096);
#pragma unroll
      for (int jj = 0; jj < 2; ++jj)
        __builtin_amdgcn_global_load_lds((const AS1 void*)(s + (size_t)jj * (64 * 4096)),
                                         (AS3 void*)(smem + d + (size_t)jj * 8192), 16, 0, 0);
    }
  };
  auto stage_B = [&](int t, int half, int p) {
    if (t >= NKT) return;
    const char* s = pB + (size_t)t * 128 + (size_t)half * (128 * 4096);
    const size_t d = (size_t)p * BUFSZ + ABUF + (size_t)half * 16384 + (size_t)tid * 16;
#pragma unroll
    for (int jj = 0; jj < 2; ++jj)
      __builtin_amdgcn_global_load_lds((const AS1 void*)(s + (size_t)jj * (64 * 4096)),
                                       (AS3 void*)(smem + d + (size_t)jj * 8192), 16, 0, 0);
  };

  // swizzled ds_read fragment addressing (slab-aligned ownership)
  const int lm = l & 15, hi4 = l >> 4;
  const int xorv = (l & 7) << 4;
  const int cb0 = (hi4 * 16) ^ xorv;
  const int cb1 = (64 + hi4 * 16) ^ xorv;
  const int aslab = (wr * 64 + lm) * 128;
  const int bslab = ABUF + (wc * 16 * NH + lm) * 128;

#define AROW(M) (((M) < 4) ? (M) * 16 : 128 + ((M) - 4) * 16)
#define BROW(N) (((N) < NH) ? (N) * 16 : BN / 2 + ((N) - NH) * 16)
#define RD_A(P, M, KS) (*(const bf16x8*)(smem + (size_t)(P) * BUFSZ + aslab + AROW(M) * 128 + ((KS) ? cb1 : cb0)))
#define RD_B(P, N, KS) (*(const bf16x8*)(smem + (size_t)(P) * BUFSZ + bslab + BROW(N) * 128 + ((KS) ? cb1 : cb0)))
#define MFMA_(D, AV, BV) D = __builtin_amdgcn_mfma_f32_16x16x32_bf16(AV, BV, D, 0, 0, 0)
#define LDA0(P) do { _Pragma("unroll") for (int m = 0; m < 4; ++m) { a0[m][0] = RD_A(P, m, 0); a0[m][1] = RD_A(P, m, 1); } } while (0)
#define LDA1(P) do { _Pragma("unroll") for (int m = 0; m < 4; ++m) { a1[m][0] = RD_A(P, 4 + m, 0); a1[m][1] = RD_A(P, 4 + m, 1); } } while (0)
#define LDB0(P) do { _Pragma("unroll") for (int n = 0; n < NH; ++n) { b0[n][0] = RD_B(P, n, 0); b0[n][1] = RD_B(P, n, 1); } } while (0)
#define LDB1(P) do { _Pragma("unroll") for (int n = 0; n < NH; ++n) { b1[n][0] = RD_B(P, NH + n, 0); b1[n][1] = RD_B(P, NH + n, 1); } } while (0)
#define Q00() do { _Pragma("unroll") for (int m = 0; m < 4; ++m) _Pragma("unroll") for (int n = 0; n < NH; ++n) { MFMA_(acc[m][n], a0[m][0], b0[n][0]); MFMA_(acc[m][n], a0[m][1], b0[n][1]); } } while (0)
#define Q01() do { _Pragma("unroll") for (int m = 0; m < 4; ++m) _Pragma("unroll") for (int n = 0; n < NH; ++n) { MFMA_(acc[m][NH + n], a0[m][0], b1[n][0]); MFMA_(acc[m][NH + n], a0[m][1], b1[n][1]); } } while (0)
#define Q11() do { _Pragma("unroll") for (int m = 0; m < 4; ++m) _Pragma("unroll") for (int n = 0; n < NH; ++n) { MFMA_(acc[4 + m][NH + n], a1[m][0], b1[n][0]); MFMA_(acc[4 + m][NH + n], a1[m][1], b1[n][1]); } } while (0)
#define Q10() do { _Pragma("unroll") for (int m = 0; m < 4; ++m) _Pragma("unroll") for (int n = 0; n < NH; ++n) { MFMA_(acc[4 + m][n], a1[m][0], b0[n][0]); MFMA_(acc[4 + m][n], a1[m][1], b0[n][1]); } } while (0)
#define SP1 __builtin_amdgcn_s_setprio(1)
#define SP0 __builtin_amdgcn_s_setprio(0)
#define BARF() do { __builtin_amdgcn_s_barrier(); asm volatile("" ::: "memory"); } while (0)

  f32x4 acc[8][WN] = {};
  bf16x8 a0[4][2], a1[4][2], b0[NH][2], b1[NH][2];

  // ---- prologue: tile0 fully + tile1 {Ah0,Bh0[,Bh1]}; confirm tile0 landed
  stage_A(0, 0, 0); stage_A(0, 1, 0); stage_B(0, 0, 0);
  if (BN == 256) stage_B(0, 1, 0);
  stage_A(1, 0, 1); stage_B(1, 0, 1);
  if (BN == 256) stage_B(1, 1, 1);
  asm volatile("s_waitcnt vmcnt(%0)" ::"i"(VCNT) : "memory");
  BARF();

  for (int it = 0; it < NIT; ++it) {
    const int o = 2 * it + 1, e2 = 2 * it + 2, o2 = 2 * it + 3;
    const bool last = (it == NIT - 1);

    // ph0: reads e.a0,e.b0 (compiler counted waits); stage o.Ah1->buf1; Q00(e); late e.b1
    LDA0(0); LDB0(0);
    stage_A(o, 1, 1);
    SP1; Q00(); SP0;
    LDB1(0);
    BARF();

    // ph1: stage e2.Ah0->buf0; Q01(e); late e.a1
    stage_A(e2, 0, 0);
    SP1; Q01(); SP0;
    LDA1(0);
    BARF();

    // ph2: stage e2.Bh0->buf0; Q11(e)
    stage_B(e2, 0, 0);
    SP1; Q11(); SP0;
    BARF();

    // ph3: stage e2.Bh1->buf0 (BN=256); Q10(e); vmcnt checkpoint
    if (BN == 256) stage_B(e2, 1, 0);
    SP1; Q10(); SP0;
    if (last) asm volatile("s_waitcnt vmcnt(0)" ::: "memory");
    else      asm volatile("s_waitcnt vmcnt(%0)" ::"i"(VCNT) : "memory");
    BARF();

    // ph4: reads o.a0,o.b0 (buf1); stage e2.Ah1->buf0; Q00(o); late o.b1
    LDA0(1); LDB0(1);
    stage_A(e2, 1, 0);
    SP1; Q00(); SP0;
    LDB1(1);
    BARF();

    // ph5: stage o2.Ah0->buf1; Q01(o); late o.a1
    stage_A(o2, 0, 1);
    SP1; Q01(); SP0;
    LDA1(1);
    BARF();

    // ph6: stage o2.Bh0->buf1; Q11(o)
    stage_B(o2, 0, 1);
    SP1; Q11(); SP0;
    BARF();

    // ph7: stage o2.Bh1->buf1 (BN=256); Q10(o); vmcnt checkpoint
    if (BN == 256) stage_B(o2, 1, 1);
    SP1; Q10(); SP0;
    if (!last) asm volatile("s_waitcnt vmcnt(%0)" ::"i"(VCNT) : "memory");
    BARF();
  }

  // ---- epilogue: C/D layout col=lane&15, row=(lane>>4)*4+j; slab ownership
#pragma unroll
  for (int m = 0; m < 8; ++m) {
#pragma unroll
    for (int n = 0; n < WN; ++n) {
      const int col = col0 + wc * 16 * NH + BROW(n) + lm;
      const int rowb = row0 + wr * 64 + AROW(m) + hi4 * 4;
#pragma unroll
      for (int j = 0; j < 4; ++j) {
        const int row = rowb + j;
        float v = acc[m][n][j];
        if (EPI == 0) {
          if (col < 1024) {
            float uv = 1.f / (1.f + __expf(-(v + bias0[col])));
            u_out[(size_t)row * 1024 + col] = f2bf(uv);
          } else {
            int c2 = col - 1024;
            float rv = 1.f / (1.f + __expf(-(v + bias1[c2])));
            float hv = hfull[(size_t)row * 1024 + c2];
            hr_out[(size_t)row * 1024 + c2] = f2bf(hv * rv);
          }
        } else {
          float cp = tanhf(v + bias0[col]);
          float uv = bf2f(u_in[(size_t)row * 1024 + col]);
          float hv = hfull[(size_t)row * 1024 + col];
          out[(size_t)row * 1024 + col] = uv * cp + (1.f - uv) * hv;
        }
      }
    }
  }
#undef AROW
#undef BROW
#undef RD_A
#undef RD_B
#undef MFMA_
#undef LDA0
#undef LDA1
#undef LDB0
#undef LDB1
#undef Q00
#undef Q01
#undef Q11
#undef Q10
#undef SP1
#undef SP0
#undef BARF
}

extern "C" void kernel_launch(void* const* d_in, const int* in_sizes, int n_in,
                              void* d_out, int out_size, void* d_ws, size_t ws_size,
                              hipStream_t stream) {
  const float* x   = (const float*)d_in[0];
  const float* h   = (const float*)d_in[1];
  const float* Wxu = (const float*)d_in[2];
  const float* Whu = (const float*)d_in[3];
  const float* bu  = (const float*)d_in[4];
  const float* Wxr = (const float*)d_in[5];
  const float* Whr = (const float*)d_in[6];
  const float* br  = (const float*)d_in[7];
  const float* Wxc = (const float*)d_in[8];
  const float* Whc = (const float*)d_in[9];
  const float* bc  = (const float*)d_in[10];
  float* out = (float*)d_out;

  char* ws = (char*)d_ws;
  unsigned short* xh  = (unsigned short*)(ws);              // 33,554,432 B
  unsigned short* Bt1 = (unsigned short*)(ws + 33554432);   //  8,388,608 B [2048][2048]
  unsigned short* Bt2 = (unsigned short*)(ws + 41943040);   //  4,194,304 B [1024][2048]
  unsigned short* ubf = (unsigned short*)(ws + 46137344);   // 16,777,216 B
  unsigned short* hrb = (unsigned short*)(ws + 62914560);   // 16,777,216 B

  pack_xh<<<4096, 256, 0, stream>>>(x, h, xh);
  transpose_pack6<<<dim3(32, 32, 6), dim3(32, 8), 0, stream>>>(Wxu, Whu, Wxr, Whr, Wxc, Whc, Bt1, Bt2);

  // GEMM1: [x|h](8192x2048) @ Bt1 -> u (bf16), hr=h*r (bf16)
  gru_gemm8<0, 256><<<dim3(8, 32), 512, 0, stream>>>(xh, nullptr, Bt1, bu, br, h,
                                                     nullptr, ubf, hrb, nullptr);
  // GEMM2: [x|hr](8192x2048) @ Bt2 -> out f32
  gru_gemm8<1, 128><<<dim3(8, 32), 512, 0, stream>>>(xh, hrb, Bt2, bc, nullptr, h,
                                                     ubf, nullptr, nullptr, out);
}

// Round 8
// 172.394 us; speedup vs baseline: 1.3809x; 1.0973x over previous
//
#include <hip/hip_runtime.h>
#include <stdint.h>

typedef float f32x4 __attribute__((ext_vector_type(4)));
typedef __bf16 bf16x8 __attribute__((ext_vector_type(8)));

#define AS1 __attribute__((address_space(1)))
#define AS3 __attribute__((address_space(3)))

__device__ __forceinline__ unsigned short f2bf(float f) {
  uint32_t u = __builtin_bit_cast(uint32_t, f);
  return (unsigned short)((u + 0x7fffu + ((u >> 16) & 1u)) >> 16);
}
__device__ __forceinline__ float bf2f(unsigned short s) {
  uint32_t u = ((uint32_t)s) << 16;
  return __builtin_bit_cast(float, u);
}

// ---- pack x,h (f32) -> xh bf16 [8192][2048]
__global__ void pack_xh(const float* __restrict__ x, const float* __restrict__ h,
                        unsigned short* __restrict__ xh) {
  const int n4 = (8192 * 1024) / 4;
  const float4* x4 = (const float4*)x;
  const float4* h4 = (const float4*)h;
  for (int idx = blockIdx.x * blockDim.x + threadIdx.x; idx < n4;
       idx += gridDim.x * blockDim.x) {
    float4 vx = x4[idx];
    float4 vh = h4[idx];
    int row = idx >> 8;
    int c = (idx & 255) << 2;
    ushort4 px = { f2bf(vx.x), f2bf(vx.y), f2bf(vx.z), f2bf(vx.w) };
    ushort4 ph = { f2bf(vh.x), f2bf(vh.y), f2bf(vh.z), f2bf(vh.w) };
    *(ushort4*)(xh + (size_t)row * 2048 + c) = px;
    *(ushort4*)(xh + (size_t)row * 2048 + 1024 + c) = ph;
  }
}

// ---- all six W (K x N f32) -> bf16 Bt (N x K) transposes in one launch
__global__ void transpose_pack6(const float* __restrict__ W0, const float* __restrict__ W1,
                                const float* __restrict__ W2, const float* __restrict__ W3,
                                const float* __restrict__ W4, const float* __restrict__ W5,
                                unsigned short* __restrict__ Bt1, unsigned short* __restrict__ Bt2) {
  __shared__ float t[32][33];
  const float* W; unsigned short* dst; int rowOff, colOff;
  switch (blockIdx.z) {
    case 0: W = W0; dst = Bt1; rowOff = 0;    colOff = 0;    break;
    case 1: W = W1; dst = Bt1; rowOff = 0;    colOff = 1024; break;
    case 2: W = W2; dst = Bt1; rowOff = 1024; colOff = 0;    break;
    case 3: W = W3; dst = Bt1; rowOff = 1024; colOff = 1024; break;
    case 4: W = W4; dst = Bt2; rowOff = 0;    colOff = 0;    break;
    default: W = W5; dst = Bt2; rowOff = 0;   colOff = 1024; break;
  }
  int n0 = blockIdx.x * 32, k0 = blockIdx.y * 32;
  for (int i = threadIdx.y; i < 32; i += 8)
    t[i][threadIdx.x] = W[(size_t)(k0 + i) * 1024 + n0 + threadIdx.x];
  __syncthreads();
  for (int i = threadIdx.y; i < 32; i += 8) {
    int n = n0 + i, k = k0 + threadIdx.x;
    dst[(size_t)(rowOff + n) * 2048 + colOff + k] = f2bf(t[threadIdx.x][i]);
  }
}

// ---- 8-phase GEMM + T1 XCD chunk swizzle. BM=256, BK=64, 8 waves (2Mx4N),
// 2 K-tiles/iter, vmcnt(VCNT) at ph3/ph7 only, T2 both-sides swizzle, T5 setprio,
// compiler-managed lgkm waits, 1 barrier/phase, slab-aligned wave ownership.
// Grid MUST be 1D with 256 blocks (8 XCD chunks of 32).
template <int EPI, int BN>
__global__ __launch_bounds__(512, 1) void gru_gemm8(
    const unsigned short* __restrict__ xh,
    const unsigned short* __restrict__ hrA,
    const unsigned short* __restrict__ Bt,
    const float* __restrict__ bias0,
    const float* __restrict__ bias1,
    const unsigned short* __restrict__ u_in,
    unsigned short* __restrict__ u_out,
    unsigned short* __restrict__ hr_out,
    float* __restrict__ out) {
  constexpr int WN = BN / 64;
  constexpr int NH = WN / 2;
  constexpr int ABUF = 32768;
  constexpr int BBUF = BN * 128;
  constexpr int BUFSZ = ABUF + BBUF;
  constexpr int NKT = 32;
  constexpr int NIT = NKT / 2;
  constexpr int VCNT = (BN == 256) ? 6 : 4;
  __shared__ __align__(128) char smem[2 * BUFSZ];

  const int tid = threadIdx.x;
  const int l = tid & 63;
  const int wid = tid >> 6;
  const int wr = wid >> 2, wc = wid & 3;

  // T1: XCD chunk swizzle — dispatch id d runs round-robin over 8 XCDs;
  // remap so XCD k computes 32 consecutive tiles (4 M-bands x all 8 N-cols).
  const int d = blockIdx.x;
  const int s = ((d & 7) << 5) + (d >> 3);  // bijective for 256 blocks
  const int tx = s & 7, ty = s >> 3;
  const int row0 = ty * 256;
  const int col0 = tx * BN;

  // staging source (inverse-swizzled global addr; LDS dest linear)
  const int srow = tid >> 3;
  const int s0 = (tid & 7) ^ (srow & 7);
  const char* pAx = (const char*)xh + (size_t)(row0 + srow) * 4096 + s0 * 16;
  const char* pAh = (EPI == 1)
      ? (const char*)hrA + (size_t)(row0 + srow) * 2048 + s0 * 16
      : (const char*)xh;
  const char* pB = (const char*)Bt + (size_t)(col0 + srow) * 4096 + s0 * 16;

  auto stage_A = [&](int t, int half, int p) {
    if (t >= NKT) return;
    const size_t dd = (size_t)p * BUFSZ + (size_t)half * 16384 + (size_t)tid * 16;
    if (EPI == 1 && t >= 16) {
      const char* sp = pAh + (size_t)(t - 16) * 128 + (size_t)half * (128 * 2048);
#pragma unroll
      for (int jj = 0; jj < 2; ++jj)
        __builtin_amdgcn_global_load_lds((const AS1 void*)(sp + (size_t)jj * (64 * 2048)),
                                         (AS3 void*)(smem + dd + (size_t)jj * 8192), 16, 0, 0);
    } else {
      const char* sp = pAx + (size_t)t * 128 + (size_t)half * (128 * 4096);
#pragma unroll
      for (int jj = 0; jj < 2; ++jj)
        __builtin_amdgcn_global_load_lds((const AS1 void*)(sp + (size_t)jj * (64 * 4096)),
                                         (AS3 void*)(smem + dd + (size_t)jj * 8192), 16, 0, 0);
    }
  };
  auto stage_B = [&](int t, int half, int p) {
    if (t >= NKT) return;
    const char* sp = pB + (size_t)t * 128 + (size_t)half * (128 * 4096);
    const size_t dd = (size_t)p * BUFSZ + ABUF + (size_t)half * 16384 + (size_t)tid * 16;
#pragma unroll
    for (int jj = 0; jj < 2; ++jj)
      __builtin_amdgcn_global_load_lds((const AS1 void*)(sp + (size_t)jj * (64 * 4096)),
                                       (AS3 void*)(smem + dd + (size_t)jj * 8192), 16, 0, 0);
  };

  // swizzled ds_read fragment addressing (slab-aligned ownership)
  const int lm = l & 15, hi4 = l >> 4;
  const int xorv = (l & 7) << 4;
  const int cb0 = (hi4 * 16) ^ xorv;
  const int cb1 = (64 + hi4 * 16) ^ xorv;
  const int aslab = (wr * 64 + lm) * 128;
  const int bslab = ABUF + (wc * 16 * NH + lm) * 128;

#define AROW(M) (((M) < 4) ? (M) * 16 : 128 + ((M) - 4) * 16)
#define BROW(N) (((N) < NH) ? (N) * 16 : BN / 2 + ((N) - NH) * 16)
#define RD_A(P, M, KS) (*(const bf16x8*)(smem + (size_t)(P) * BUFSZ + aslab + AROW(M) * 128 + ((KS) ? cb1 : cb0)))
#define RD_B(P, N, KS) (*(const bf16x8*)(smem + (size_t)(P) * BUFSZ + bslab + BROW(N) * 128 + ((KS) ? cb1 : cb0)))
#define MFMA_(D, AV, BV) D = __builtin_amdgcn_mfma_f32_16x16x32_bf16(AV, BV, D, 0, 0, 0)
#define LDA0(P) do { _Pragma("unroll") for (int m = 0; m < 4; ++m) { a0[m][0] = RD_A(P, m, 0); a0[m][1] = RD_A(P, m, 1); } } while (0)
#define LDA1(P) do { _Pragma("unroll") for (int m = 0; m < 4; ++m) { a1[m][0] = RD_A(P, 4 + m, 0); a1[m][1] = RD_A(P, 4 + m, 1); } } while (0)
#define LDB0(P) do { _Pragma("unroll") for (int n = 0; n < NH; ++n) { b0[n][0] = RD_B(P, n, 0); b0[n][1] = RD_B(P, n, 1); } } while (0)
#define LDB1(P) do { _Pragma("unroll") for (int n = 0; n < NH; ++n) { b1[n][0] = RD_B(P, NH + n, 0); b1[n][1] = RD_B(P, NH + n, 1); } } while (0)
#define Q00() do { _Pragma("unroll") for (int m = 0; m < 4; ++m) _Pragma("unroll") for (int n = 0; n < NH; ++n) { MFMA_(acc[m][n], a0[m][0], b0[n][0]); MFMA_(acc[m][n], a0[m][1], b0[n][1]); } } while (0)
#define Q01() do { _Pragma("unroll") for (int m = 0; m < 4; ++m) _Pragma("unroll") for (int n = 0; n < NH; ++n) { MFMA_(acc[m][NH + n], a0[m][0], b1[n][0]); MFMA_(acc[m][NH + n], a0[m][1], b1[n][1]); } } while (0)
#define Q11() do { _Pragma("unroll") for (int m = 0; m < 4; ++m) _Pragma("unroll") for (int n = 0; n < NH; ++n) { MFMA_(acc[4 + m][NH + n], a1[m][0], b1[n][0]); MFMA_(acc[4 + m][NH + n], a1[m][1], b1[n][1]); } } while (0)
#define Q10() do { _Pragma("unroll") for (int m = 0; m < 4; ++m) _Pragma("unroll") for (int n = 0; n < NH; ++n) { MFMA_(acc[4 + m][n], a1[m][0], b0[n][0]); MFMA_(acc[4 + m][n], a1[m][1], b0[n][1]); } } while (0)
#define SP1 __builtin_amdgcn_s_setprio(1)
#define SP0 __builtin_amdgcn_s_setprio(0)
#define BARF() do { __builtin_amdgcn_s_barrier(); asm volatile("" ::: "memory"); } while (0)

  f32x4 acc[8][WN] = {};
  bf16x8 a0[4][2], a1[4][2], b0[NH][2], b1[NH][2];

  // ---- prologue: tile0 fully + tile1 {Ah0,Bh0[,Bh1]}; confirm tile0 landed
  stage_A(0, 0, 0); stage_A(0, 1, 0); stage_B(0, 0, 0);
  if (BN == 256) stage_B(0, 1, 0);
  stage_A(1, 0, 1); stage_B(1, 0, 1);
  if (BN == 256) stage_B(1, 1, 1);
  asm volatile("s_waitcnt vmcnt(%0)" ::"i"(VCNT) : "memory");
  BARF();

  for (int it = 0; it < NIT; ++it) {
    const int o = 2 * it + 1, e2 = 2 * it + 2, o2 = 2 * it + 3;
    const bool last = (it == NIT - 1);

    // ph0: reads e.a0,e.b0; stage o.Ah1->buf1; Q00(e); late e.b1
    LDA0(0); LDB0(0);
    stage_A(o, 1, 1);
    SP1; Q00(); SP0;
    LDB1(0);
    BARF();

    // ph1: stage e2.Ah0->buf0; Q01(e); late e.a1
    stage_A(e2, 0, 0);
    SP1; Q01(); SP0;
    LDA1(0);
    BARF();

    // ph2: stage e2.Bh0->buf0; Q11(e)
    stage_B(e2, 0, 0);
    SP1; Q11(); SP0;
    BARF();

    // ph3: stage e2.Bh1->buf0 (BN=256); Q10(e); vmcnt checkpoint
    if (BN == 256) stage_B(e2, 1, 0);
    SP1; Q10(); SP0;
    if (last) asm volatile("s_waitcnt vmcnt(0)" ::: "memory");
    else      asm volatile("s_waitcnt vmcnt(%0)" ::"i"(VCNT) : "memory");
    BARF();

    // ph4: reads o.a0,o.b0 (buf1); stage e2.Ah1->buf0; Q00(o); late o.b1
    LDA0(1); LDB0(1);
    stage_A(e2, 1, 0);
    SP1; Q00(); SP0;
    LDB1(1);
    BARF();

    // ph5: stage o2.Ah0->buf1; Q01(o); late o.a1
    stage_A(o2, 0, 1);
    SP1; Q01(); SP0;
    LDA1(1);
    BARF();

    // ph6: stage o2.Bh0->buf1; Q11(o)
    stage_B(o2, 0, 1);
    SP1; Q11(); SP0;
    BARF();

    // ph7: stage o2.Bh1->buf1 (BN=256); Q10(o); vmcnt checkpoint
    if (BN == 256) stage_B(o2, 1, 1);
    SP1; Q10(); SP0;
    if (!last) asm volatile("s_waitcnt vmcnt(%0)" ::"i"(VCNT) : "memory");
    BARF();
  }

  // ---- epilogue: C/D layout col=lane&15, row=(lane>>4)*4+j; slab ownership.
  // h is read as bf16 from xh's h-half (cols 1024..2047) — saves 16 MB f32 reads.
#pragma unroll
  for (int m = 0; m < 8; ++m) {
#pragma unroll
    for (int n = 0; n < WN; ++n) {
      const int col = col0 + wc * 16 * NH + BROW(n) + lm;
      const int rowb = row0 + wr * 64 + AROW(m) + hi4 * 4;
#pragma unroll
      for (int j = 0; j < 4; ++j) {
        const int row = rowb + j;
        float v = acc[m][n][j];
        if (EPI == 0) {
          if (col < 1024) {
            float uv = 1.f / (1.f + __expf(-(v + bias0[col])));
            u_out[(size_t)row * 1024 + col] = f2bf(uv);
          } else {
            int c2 = col - 1024;
            float rv = 1.f / (1.f + __expf(-(v + bias1[c2])));
            float hv = bf2f(xh[(size_t)row * 2048 + 1024 + c2]);
            hr_out[(size_t)row * 1024 + c2] = f2bf(hv * rv);
          }
        } else {
          float cp = tanhf(v + bias0[col]);
          float uv = bf2f(u_in[(size_t)row * 1024 + col]);
          float hv = bf2f(xh[(size_t)row * 2048 + 1024 + col]);
          out[(size_t)row * 1024 + col] = uv * cp + (1.f - uv) * hv;
        }
      }
    }
  }
#undef AROW
#undef BROW
#undef RD_A
#undef RD_B
#undef MFMA_
#undef LDA0
#undef LDA1
#undef LDB0
#undef LDB1
#undef Q00
#undef Q01
#undef Q11
#undef Q10
#undef SP1
#undef SP0
#undef BARF
}

extern "C" void kernel_launch(void* const* d_in, const int* in_sizes, int n_in,
                              void* d_out, int out_size, void* d_ws, size_t ws_size,
                              hipStream_t stream) {
  const float* x   = (const float*)d_in[0];
  const float* h   = (const float*)d_in[1];
  const float* Wxu = (const float*)d_in[2];
  const float* Whu = (const float*)d_in[3];
  const float* bu  = (const float*)d_in[4];
  const float* Wxr = (const float*)d_in[5];
  const float* Whr = (const float*)d_in[6];
  const float* br  = (const float*)d_in[7];
  const float* Wxc = (const float*)d_in[8];
  const float* Whc = (const float*)d_in[9];
  const float* bc  = (const float*)d_in[10];
  float* out = (float*)d_out;

  char* ws = (char*)d_ws;
  unsigned short* xh  = (unsigned short*)(ws);              // 33,554,432 B
  unsigned short* Bt1 = (unsigned short*)(ws + 33554432);   //  8,388,608 B [2048][2048]
  unsigned short* Bt2 = (unsigned short*)(ws + 41943040);   //  4,194,304 B [1024][2048]
  unsigned short* ubf = (unsigned short*)(ws + 46137344);   // 16,777,216 B
  unsigned short* hrb = (unsigned short*)(ws + 62914560);   // 16,777,216 B

  pack_xh<<<4096, 256, 0, stream>>>(x, h, xh);
  transpose_pack6<<<dim3(32, 32, 6), dim3(32, 8), 0, stream>>>(Wxu, Whu, Wxr, Whr, Wxc, Whc, Bt1, Bt2);

  // GEMM1: [x|h](8192x2048) @ Bt1 -> u (bf16), hr=h*r (bf16).  1D grid, XCD-swizzled.
  gru_gemm8<0, 256><<<256, 512, 0, stream>>>(xh, nullptr, Bt1, bu, br,
                                             nullptr, ubf, hrb, nullptr);
  // GEMM2: [x|hr](8192x2048) @ Bt2 -> out f32.
  gru_gemm8<1, 128><<<256, 512, 0, stream>>>(xh, hrb, Bt2, bc, nullptr,
                                             ubf, nullptr, nullptr, out);
}

// Round 9
// 155.027 us; speedup vs baseline: 1.5356x; 1.1120x over previous
//
#include <hip/hip_runtime.h>
#include <stdint.h>

typedef float f32x4 __attribute__((ext_vector_type(4)));
typedef __bf16 bf16x8 __attribute__((ext_vector_type(8)));

#define AS1 __attribute__((address_space(1)))
#define AS3 __attribute__((address_space(3)))

__device__ __forceinline__ unsigned short f2bf(float f) {
  uint32_t u = __builtin_bit_cast(uint32_t, f);
  return (unsigned short)((u + 0x7fffu + ((u >> 16) & 1u)) >> 16);
}
__device__ __forceinline__ float bf2f(unsigned short s) {
  uint32_t u = ((uint32_t)s) << 16;
  return __builtin_bit_cast(float, u);
}

// ---- pack x,h (f32) -> xh bf16 [8192][2048]
__global__ void pack_xh(const float* __restrict__ x, const float* __restrict__ h,
                        unsigned short* __restrict__ xh) {
  const int n4 = (8192 * 1024) / 4;
  const float4* x4 = (const float4*)x;
  const float4* h4 = (const float4*)h;
  for (int idx = blockIdx.x * blockDim.x + threadIdx.x; idx < n4;
       idx += gridDim.x * blockDim.x) {
    float4 vx = x4[idx];
    float4 vh = h4[idx];
    int row = idx >> 8;
    int c = (idx & 255) << 2;
    ushort4 px = { f2bf(vx.x), f2bf(vx.y), f2bf(vx.z), f2bf(vx.w) };
    ushort4 ph = { f2bf(vh.x), f2bf(vh.y), f2bf(vh.z), f2bf(vh.w) };
    *(ushort4*)(xh + (size_t)row * 2048 + c) = px;
    *(ushort4*)(xh + (size_t)row * 2048 + 1024 + c) = ph;
  }
}

// ---- all six W (K x N f32) -> bf16 Bt (N x K) transposes in one launch
__global__ void transpose_pack6(const float* __restrict__ W0, const float* __restrict__ W1,
                                const float* __restrict__ W2, const float* __restrict__ W3,
                                const float* __restrict__ W4, const float* __restrict__ W5,
                                unsigned short* __restrict__ Bt1, unsigned short* __restrict__ Bt2) {
  __shared__ float t[32][33];
  const float* W; unsigned short* dst; int rowOff, colOff;
  switch (blockIdx.z) {
    case 0: W = W0; dst = Bt1; rowOff = 0;    colOff = 0;    break;
    case 1: W = W1; dst = Bt1; rowOff = 0;    colOff = 1024; break;
    case 2: W = W2; dst = Bt1; rowOff = 1024; colOff = 0;    break;
    case 3: W = W3; dst = Bt1; rowOff = 1024; colOff = 1024; break;
    case 4: W = W4; dst = Bt2; rowOff = 0;    colOff = 0;    break;
    default: W = W5; dst = Bt2; rowOff = 0;   colOff = 1024; break;
  }
  int n0 = blockIdx.x * 32, k0 = blockIdx.y * 32;
  for (int i = threadIdx.y; i < 32; i += 8)
    t[i][threadIdx.x] = W[(size_t)(k0 + i) * 1024 + n0 + threadIdx.x];
  __syncthreads();
  for (int i = threadIdx.y; i < 32; i += 8) {
    int n = n0 + i, k = k0 + threadIdx.x;
    dst[(size_t)(rowOff + n) * 2048 + colOff + k] = f2bf(t[threadIdx.x][i]);
  }
}

// ---- 8-phase GEMM, ALL-LATE ds_reads (every read issued >=1 barrier before its
// consuming MFMA), checkpoints at ph2/ph6 (VCNT=4), T1 XCD chunk swizzle,
// T2 both-sides LDS swizzle, T5 setprio, slab-aligned wave ownership.
// BM=256, BK=64, 8 waves (2Mx4N), 2 K-tiles/iter. Grid: 1D, 256 blocks.
template <int EPI, int BN>
__global__ __launch_bounds__(512, 1) void gru_gemm8(
    const unsigned short* __restrict__ xh,
    const unsigned short* __restrict__ hrA,
    const unsigned short* __restrict__ Bt,
    const float* __restrict__ bias0,
    const float* __restrict__ bias1,
    const unsigned short* __restrict__ u_in,
    unsigned short* __restrict__ u_out,
    unsigned short* __restrict__ hr_out,
    float* __restrict__ out) {
  constexpr int WN = BN / 64;
  constexpr int NH = WN / 2;
  constexpr int ABUF = 32768;
  constexpr int BBUF = BN * 128;
  constexpr int BUFSZ = ABUF + BBUF;
  constexpr int NKT = 32;
  constexpr int NIT = NKT / 2;
  constexpr int VCNT = 4;  // ledger: confirms the full next tile at ph2/ph6 (both BN)
  __shared__ __align__(128) char smem[2 * BUFSZ];

  const int tid = threadIdx.x;
  const int l = tid & 63;
  const int wid = tid >> 6;
  const int wr = wid >> 2, wc = wid & 3;

  // T1: XCD chunk swizzle (256 blocks = 8 chunks of 32)
  const int d = blockIdx.x;
  const int s = ((d & 7) << 5) + (d >> 3);
  const int tx = s & 7, ty = s >> 3;
  const int row0 = ty * 256;
  const int col0 = tx * BN;

  // staging source (inverse-swizzled global addr; LDS dest linear)
  const int srow = tid >> 3;
  const int s0 = (tid & 7) ^ (srow & 7);
  const char* pAx = (const char*)xh + (size_t)(row0 + srow) * 4096 + s0 * 16;
  const char* pAh = (EPI == 1)
      ? (const char*)hrA + (size_t)(row0 + srow) * 2048 + s0 * 16
      : (const char*)xh;
  const char* pB = (const char*)Bt + (size_t)(col0 + srow) * 4096 + s0 * 16;

  auto stage_A = [&](int t, int half, int p) {
    if (t >= NKT) return;
    const size_t dd = (size_t)p * BUFSZ + (size_t)half * 16384 + (size_t)tid * 16;
    if (EPI == 1 && t >= 16) {
      const char* sp = pAh + (size_t)(t - 16) * 128 + (size_t)half * (128 * 2048);
#pragma unroll
      for (int jj = 0; jj < 2; ++jj)
        __builtin_amdgcn_global_load_lds((const AS1 void*)(sp + (size_t)jj * (64 * 2048)),
                                         (AS3 void*)(smem + dd + (size_t)jj * 8192), 16, 0, 0);
    } else {
      const char* sp = pAx + (size_t)t * 128 + (size_t)half * (128 * 4096);
#pragma unroll
      for (int jj = 0; jj < 2; ++jj)
        __builtin_amdgcn_global_load_lds((const AS1 void*)(sp + (size_t)jj * (64 * 4096)),
                                         (AS3 void*)(smem + dd + (size_t)jj * 8192), 16, 0, 0);
    }
  };
  auto stage_B = [&](int t, int half, int p) {
    if (t >= NKT) return;
    const char* sp = pB + (size_t)t * 128 + (size_t)half * (128 * 4096);
    const size_t dd = (size_t)p * BUFSZ + ABUF + (size_t)half * 16384 + (size_t)tid * 16;
#pragma unroll
    for (int jj = 0; jj < 2; ++jj)
      __builtin_amdgcn_global_load_lds((const AS1 void*)(sp + (size_t)jj * (64 * 4096)),
                                       (AS3 void*)(smem + dd + (size_t)jj * 8192), 16, 0, 0);
  };

  // swizzled ds_read fragment addressing (slab-aligned ownership)
  const int lm = l & 15, hi4 = l >> 4;
  const int xorv = (l & 7) << 4;
  const int cb0 = (hi4 * 16) ^ xorv;
  const int cb1 = (64 + hi4 * 16) ^ xorv;
  const int aslab = (wr * 64 + lm) * 128;
  const int bslab = ABUF + (wc * 16 * NH + lm) * 128;

#define AROW(M) (((M) < 4) ? (M) * 16 : 128 + ((M) - 4) * 16)
#define BROW(N) (((N) < NH) ? (N) * 16 : BN / 2 + ((N) - NH) * 16)
#define RD_A(P, M, KS) (*(const bf16x8*)(smem + (size_t)(P) * BUFSZ + aslab + AROW(M) * 128 + ((KS) ? cb1 : cb0)))
#define RD_B(P, N, KS) (*(const bf16x8*)(smem + (size_t)(P) * BUFSZ + bslab + BROW(N) * 128 + ((KS) ? cb1 : cb0)))
#define MFMA_(D, AV, BV) D = __builtin_amdgcn_mfma_f32_16x16x32_bf16(AV, BV, D, 0, 0, 0)
#define LDA0(P) do { _Pragma("unroll") for (int m = 0; m < 4; ++m) { a0[m][0] = RD_A(P, m, 0); a0[m][1] = RD_A(P, m, 1); } } while (0)
#define LDA1(P) do { _Pragma("unroll") for (int m = 0; m < 4; ++m) { a1[m][0] = RD_A(P, 4 + m, 0); a1[m][1] = RD_A(P, 4 + m, 1); } } while (0)
#define LDB0(P) do { _Pragma("unroll") for (int n = 0; n < NH; ++n) { b0[n][0] = RD_B(P, n, 0); b0[n][1] = RD_B(P, n, 1); } } while (0)
#define LDB1(P) do { _Pragma("unroll") for (int n = 0; n < NH; ++n) { b1[n][0] = RD_B(P, NH + n, 0); b1[n][1] = RD_B(P, NH + n, 1); } } while (0)
#define Q00() do { _Pragma("unroll") for (int m = 0; m < 4; ++m) _Pragma("unroll") for (int n = 0; n < NH; ++n) { MFMA_(acc[m][n], a0[m][0], b0[n][0]); MFMA_(acc[m][n], a0[m][1], b0[n][1]); } } while (0)
#define Q01() do { _Pragma("unroll") for (int m = 0; m < 4; ++m) _Pragma("unroll") for (int n = 0; n < NH; ++n) { MFMA_(acc[m][NH + n], a0[m][0], b1[n][0]); MFMA_(acc[m][NH + n], a0[m][1], b1[n][1]); } } while (0)
#define Q11() do { _Pragma("unroll") for (int m = 0; m < 4; ++m) _Pragma("unroll") for (int n = 0; n < NH; ++n) { MFMA_(acc[4 + m][NH + n], a1[m][0], b1[n][0]); MFMA_(acc[4 + m][NH + n], a1[m][1], b1[n][1]); } } while (0)
#define Q10() do { _Pragma("unroll") for (int m = 0; m < 4; ++m) _Pragma("unroll") for (int n = 0; n < NH; ++n) { MFMA_(acc[4 + m][n], a1[m][0], b0[n][0]); MFMA_(acc[4 + m][n], a1[m][1], b0[n][1]); } } while (0)
#define SP1 __builtin_amdgcn_s_setprio(1)
#define SP0 __builtin_amdgcn_s_setprio(0)
#define BARF() do { __builtin_amdgcn_s_barrier(); asm volatile("" ::: "memory"); } while (0)

  f32x4 acc[8][WN] = {};
  bf16x8 a0[4][2], a1[4][2], b0[NH][2], b1[NH][2];

  // ---- prologue: stage tile0 fully + tile1 {Ah0,B(h0[,h1])}; confirm tile0;
  // pre-read tile0's a0,b0 so ph0 has zero sync reads.
  stage_A(0, 0, 0); stage_A(0, 1, 0); stage_B(0, 0, 0);
  if (BN == 256) stage_B(0, 1, 0);
  stage_A(1, 0, 1); stage_B(1, 0, 1);
  if (BN == 256) stage_B(1, 1, 1);
  asm volatile("s_waitcnt vmcnt(%0)" ::"i"(BN == 256 ? 6 : 4) : "memory");
  BARF();
  LDA0(0); LDB0(0);

  for (int it = 0; it < NIT; ++it) {
    const int o = 2 * it + 1, e2 = 2 * it + 2, o2 = 2 * it + 3;
    const bool last = (it == NIT - 1);

    // ph0: stage o.Ah1->buf1; Q00(e) [a0,b0 preloaded]; late: e.b1
    stage_A(o, 1, 1);
    SP1; Q00(); SP0;
    LDB1(0);
    BARF();

    // ph1: stage e2.Ah0->buf0; Q01(e); late: e.a1
    stage_A(e2, 0, 0);
    SP1; Q01(); SP0;
    LDA1(0);
    BARF();

    // ph2: stage e2.Bh0->buf0; Q11(e); checkpoint (confirms ALL of tile o)
    stage_B(e2, 0, 0);
    SP1; Q11(); SP0;
    if (last) asm volatile("s_waitcnt vmcnt(0)" ::: "memory");
    else      asm volatile("s_waitcnt vmcnt(%0)" ::"i"(VCNT) : "memory");
    BARF();

    // ph3: stage e2.Bh1->buf0 (BN=256); Q10(e); late: o.a0,o.b0 (confirmed @ph2)
    if (BN == 256) stage_B(e2, 1, 0);
    SP1; Q10(); SP0;
    LDA0(1); LDB0(1);
    BARF();

    // ph4: stage e2.Ah1->buf0; Q00(o); late: o.b1
    stage_A(e2, 1, 0);
    SP1; Q00(); SP0;
    LDB1(1);
    BARF();

    // ph5: stage o2.Ah0->buf1; Q01(o); late: o.a1
    stage_A(o2, 0, 1);
    SP1; Q01(); SP0;
    LDA1(1);
    BARF();

    // ph6: stage o2.Bh0->buf1; Q11(o); checkpoint (confirms ALL of tile e2)
    stage_B(o2, 0, 1);
    SP1; Q11(); SP0;
    if (last) asm volatile("s_waitcnt vmcnt(0)" ::: "memory");
    else      asm volatile("s_waitcnt vmcnt(%0)" ::"i"(VCNT) : "memory");
    BARF();

    // ph7: stage o2.Bh1->buf1 (BN=256); Q10(o); late: e2.a0,e2.b0 (skip on last)
    if (BN == 256) stage_B(o2, 1, 1);
    SP1; Q10(); SP0;
    if (!last) { LDA0(0); LDB0(0); }
    BARF();
  }

  // ---- epilogue: C/D layout col=lane&15, row=(lane>>4)*4+j; slab ownership.
#pragma unroll
  for (int m = 0; m < 8; ++m) {
#pragma unroll
    for (int n = 0; n < WN; ++n) {
      const int col = col0 + wc * 16 * NH + BROW(n) + lm;
      const int rowb = row0 + wr * 64 + AROW(m) + hi4 * 4;
#pragma unroll
      for (int j = 0; j < 4; ++j) {
        const int row = rowb + j;
        float v = acc[m][n][j];
        if (EPI == 0) {
          if (col < 1024) {
            float uv = 1.f / (1.f + __expf(-(v + bias0[col])));
            u_out[(size_t)row * 1024 + col] = f2bf(uv);
          } else {
            int c2 = col - 1024;
            float rv = 1.f / (1.f + __expf(-(v + bias1[c2])));
            float hv = bf2f(xh[(size_t)row * 2048 + 1024 + c2]);
            hr_out[(size_t)row * 1024 + c2] = f2bf(hv * rv);
          }
        } else {
          float e2x = __expf(2.f * (v + bias0[col]));
          float cp = (e2x - 1.f) / (e2x + 1.f);
          float uv = bf2f(u_in[(size_t)row * 1024 + col]);
          float hv = bf2f(xh[(size_t)row * 2048 + 1024 + col]);
          out[(size_t)row * 1024 + col] = uv * cp + (1.f - uv) * hv;
        }
      }
    }
  }
#undef AROW
#undef BROW
#undef RD_A
#undef RD_B
#undef MFMA_
#undef LDA0
#undef LDA1
#undef LDB0
#undef LDB1
#undef Q00
#undef Q01
#undef Q11
#undef Q10
#undef SP1
#undef SP0
#undef BARF
}

extern "C" void kernel_launch(void* const* d_in, const int* in_sizes, int n_in,
                              void* d_out, int out_size, void* d_ws, size_t ws_size,
                              hipStream_t stream) {
  const float* x   = (const float*)d_in[0];
  const float* h   = (const float*)d_in[1];
  const float* Wxu = (const float*)d_in[2];
  const float* Whu = (const float*)d_in[3];
  const float* bu  = (const float*)d_in[4];
  const float* Wxr = (const float*)d_in[5];
  const float* Whr = (const float*)d_in[6];
  const float* br  = (const float*)d_in[7];
  const float* Wxc = (const float*)d_in[8];
  const float* Whc = (const float*)d_in[9];
  const float* bc  = (const float*)d_in[10];
  float* out = (float*)d_out;

  char* ws = (char*)d_ws;
  unsigned short* xh  = (unsigned short*)(ws);              // 33,554,432 B
  unsigned short* Bt1 = (unsigned short*)(ws + 33554432);   //  8,388,608 B
  unsigned short* Bt2 = (unsigned short*)(ws + 41943040);   //  4,194,304 B
  unsigned short* ubf = (unsigned short*)(ws + 46137344);   // 16,777,216 B
  unsigned short* hrb = (unsigned short*)(ws + 62914560);   // 16,777,216 B

  pack_xh<<<4096, 256, 0, stream>>>(x, h, xh);
  transpose_pack6<<<dim3(32, 32, 6), dim3(32, 8), 0, stream>>>(Wxu, Whu, Wxr, Whr, Wxc, Whc, Bt1, Bt2);

  // GEMM1: [x|h](8192x2048) @ Bt1 -> u (bf16), hr=h*r (bf16)
  gru_gemm8<0, 256><<<256, 512, 0, stream>>>(xh, nullptr, Bt1, bu, br,
                                             nullptr, ubf, hrb, nullptr);
  // GEMM2: [x|hr](8192x2048) @ Bt2 -> out f32
  gru_gemm8<1, 128><<<256, 512, 0, stream>>>(xh, hrb, Bt2, bc, nullptr,
                                             ubf, nullptr, nullptr, out);
}